// Round 1
// 155.414 us; speedup vs baseline: 1.0881x; 1.0881x over previous
//
#include <hip/hip_runtime.h>
#include <math.h>

#define N 16384
#define GC 8             // grid cells per dim (margin >= 1/8 -> fallback ~never fires)
#define NCELL (GC*GC*GC) // 512

__device__ __forceinline__ float wsum(float v){
  #pragma unroll
  for(int m=32;m>0;m>>=1) v += __shfl_xor(v,m,64);
  return v;
}

// branchless lexicographic (d,idx) top-3 insert; matches jax top_k stable tie-break
__device__ __forceinline__ void lexins(float dd,int j2,
    float&D0,float&D1,float&D2,int&I0,int&I1,int&I2){
  bool lt0=(dd<D0)||((dd==D0)&&(j2<I0));
  bool lt1=(dd<D1)||((dd==D1)&&(j2<I1));
  bool lt2=(dd<D2)||((dd==D2)&&(j2<I2));
  float nD2=lt1?D1:(lt2?dd:D2); int nI2=lt1?I1:(lt2?j2:I2);
  float nD1=lt0?D0:(lt1?dd:D1); int nI1=lt0?I0:(lt1?j2:I1);
  float nD0=lt0?dd:D0;          int nI0=lt0?j2:I0;
  D0=nD0;D1=nD1;D2=nD2;I0=nI0;I1=nI1;I2=nI2;
}

// reference-exact squared distance: dd = rn(rn(qs+cs) - 2*dot), dot FMA chain
__device__ __forceinline__ float refdist(float qx,float qy,float qz,float qs,float4 cv){
  float dot=__fmaf_rn(qz,cv.z,__fmaf_rn(qy,cv.y,__fmul_rn(qx,cv.x)));
  float sc =__fadd_rn(qs,cv.w);
  return __fmaf_rn(-2.0f,dot,sc);
}

// ---- K1: LN -> x2 -> LN, row L2 norms, c4=(x,y,z,sq), + cell histogram. ----
// One wave per row. Histogram via device-scope atomicAdd into cnt[] (zeroed by
// the 4KB memset that precedes this kernel on the stream).
__global__ __launch_bounds__(256) void ln_kernel(const float* __restrict__ in,
    const float* __restrict__ g1,const float* __restrict__ b1,
    const float* __restrict__ g2,const float* __restrict__ b2,
    const float* __restrict__ coords,
    float* __restrict__ x, float* __restrict__ xn, float4* __restrict__ c4,
    int* __restrict__ cnt){
  int wave=threadIdx.x>>6, lane=threadIdx.x&63;
  int row=blockIdx.x*4+wave;
  float v=in[row*64+lane];
  float m=wsum(v)*(1.0f/64.0f);
  float d=v-m;
  float var=wsum(d*d)*(1.0f/64.0f);
  float y=d*(1.0f/sqrtf(var+1e-5f))*g1[lane]+b1[lane];
  y=y+y;  // transformer stubbed as identity + shortcut
  float m2=wsum(y)*(1.0f/64.0f);
  float d2=y-m2;
  float var2=wsum(d2*d2)*(1.0f/64.0f);
  float z=d2*(1.0f/sqrtf(var2+1e-5f))*g2[lane]+b2[lane];
  x[row*64+lane]=z;
  float s=wsum(z*z);
  if(lane==0){
    xn[row]=fmaxf(sqrtf(s),1e-8f);
    float a=coords[row*3+0],b=coords[row*3+1],c=coords[row*3+2];
    float sq=__fadd_rn(__fadd_rn(__fmul_rn(a,a),__fmul_rn(b,b)),__fmul_rn(c,c));
    c4[row]=make_float4(a,b,c,sq);
    int cx=min(GC-1,(int)(a*(float)GC)), cy=min(GC-1,(int)(b*(float)GC)),
        cz=min(GC-1,(int)(c*(float)GC));
    atomicAdd(&cnt[(cz*GC+cy)*GC+cx],1);   // device-scope, 16384 adds / 512 cells
  }
}

// ---- K2: parallel scatter (replaces single-block prep). 64 blocks x 256. ----
// Each block redundantly computes the 512-cell exclusive scan in LDS (9 rounds,
// ~1us) -- cheaper than a serializing extra dispatch. Block 0 publishes cellSt.
// Positions via global cursor atomics; within-cell order is nondeterministic,
// which is fine: knn's top-3 uses full lexicographic (d,idx) tie-break, so the
// result is independent of sc4 ordering.
__global__ __launch_bounds__(256) void scatter_k(const float4* __restrict__ c4,
    const int* __restrict__ cnt, int* __restrict__ cursor,
    float4* __restrict__ sc4, int* __restrict__ sidx, int* __restrict__ cellSt){
  __shared__ int buf[NCELL];
  int tid=threadIdx.x;
  int c0v=cnt[tid], c1v=cnt[tid+256];
  buf[tid]=c0v; buf[tid+256]=c1v;
  __syncthreads();
  #pragma unroll
  for(int off=1;off<NCELL;off<<=1){
    int v0=(tid>=off)?buf[tid-off]:0;
    int v1=(tid+256>=off)?buf[tid+256-off]:0;
    __syncthreads();
    buf[tid]+=v0; buf[tid+256]+=v1;
    __syncthreads();
  }
  int e0=buf[tid]-c0v, e1=buf[tid+256]-c1v;   // exclusive starts
  if(blockIdx.x==0){
    cellSt[tid]=e0; cellSt[tid+256]=e1;
    if(tid==0) cellSt[NCELL]=N;
  }
  __syncthreads();
  buf[tid]=e0; buf[tid+256]=e1;               // LDS now holds exclusive starts
  __syncthreads();
  int i=blockIdx.x*256+tid;
  float4 v=c4[i];
  int cx=min(GC-1,(int)(v.x*(float)GC)), cy=min(GC-1,(int)(v.y*(float)GC)),
      cz=min(GC-1,(int)(v.z*(float)GC));
  int cell=(cz*GC+cy)*GC+cx;
  int pos=buf[cell]+atomicAdd(&cursor[cell],1);
  sc4[pos]=v; sidx[pos]=i;
}

// ---- K3: grid KNN (32 lanes/query, pruned cell runs) + edge weights. ----
// 2048 blocks x 256. Runs ordered center -> faces -> diagonals; a run is
// skipped iff its geometric lower bound dy^2+dz^2 exceeds current D2 plus
// conservative slack (1e-5 >> dd rounding error ~7e-7). Skip test is
// per-query-uniform; the whole-region margin check + fallback still
// certifies exactness, so pruning cannot change results.
__global__ __launch_bounds__(256) void knn_ew(const float4* __restrict__ sc4,
    const int* __restrict__ sidx, const int* __restrict__ cellSt,
    const float4* __restrict__ c4, const float* __restrict__ x,
    const float* __restrict__ xn,
    int* __restrict__ knn, float* __restrict__ ew, float* __restrict__ dis){
  int tid=threadIdx.x, bid=blockIdx.x;
  int gt=bid*256+tid;
  int lane=tid&63;
  int slot=gt>>5, part=tid&31;

  float4 qv=sc4[slot]; int q=sidx[slot];
  float qx=qv.x,qy=qv.y,qz=qv.z,qs=qv.w;
  int cx=min(GC-1,(int)(qx*(float)GC)), cy=min(GC-1,(int)(qy*(float)GC)),
      cz=min(GC-1,(int)(qz*(float)GC));
  float D0=1e30f,D1=1e30f,D2=1e30f; int I0=0x7fffffff,I1=0x7fffffff,I2=0x7fffffff;
  int xlo=max(cx-1,0), xhi=min(cx+1,GC-1);
  const float cw=1.0f/(float)GC;
  float fy0=qy-(float)cy*cw, fy1=(float)(cy+1)*cw-qy;   // dist to y faces
  float fz0=qz-(float)cz*cw, fz1=(float)(cz+1)*cw-qz;   // dist to z faces
  // run order: center, 4 faces, 4 diagonals  (oy, oz)
  const int OY[9]={0,-1,1, 0,0,-1, 1,-1,1};
  const int OZ[9]={0, 0,0,-1,1,-1,-1, 1,1};
  #pragma unroll 1
  for(int k=0;k<9;k++){
    int oy=OY[k], oz=OZ[k];
    int y2=cy+oy, z2=cz+oz;
    if(y2<0||y2>=GC||z2<0||z2>=GC) continue;
    if(k>0){
      float dy=(oy<0)?fy0:((oy>0)?fy1:0.0f);
      float dz=(oz<0)?fz0:((oz>0)?fz1:0.0f);
      float bnd=dy*dy+dz*dz;
      if(bnd>D2+1e-5f) continue;          // conservative skip
    }
    int rowb=(z2*GC+y2)*GC;
    int p0=cellSt[rowb+xlo], p1=cellSt[rowb+xhi+1];  // x-cells contiguous
    for(int p=p0+part;p<p1;p+=32){
      float4 cv=sc4[p]; int j2=sidx[p];
      float dd=refdist(qx,qy,qz,qs,cv);
      dd=(j2==q)?1e30f:dd;
      lexins(dd,j2,D0,D1,D2,I0,I1,I2);
    }
  }
  #pragma unroll
  for(int m=1;m<32;m<<=1){
    float e0=__shfl_xor(D0,m),e1=__shfl_xor(D1,m),e2=__shfl_xor(D2,m);
    int   f0=__shfl_xor(I0,m),f1=__shfl_xor(I1,m),f2=__shfl_xor(I2,m);
    lexins(e0,f0,D0,D1,D2,I0,I1,I2);
    lexins(e1,f1,D0,D1,D2,I0,I1,I2);
    lexins(e2,f2,D0,D1,D2,I0,I1,I2);
  }
  bool flg=false;
  if(part==0){
    float mg=1e30f;
    mg=fminf(mg,(cx>0)?(qx-(float)(cx-1)*cw):1e30f);
    mg=fminf(mg,(cx<GC-1)?((float)(cx+2)*cw-qx):1e30f);
    mg=fminf(mg,(cy>0)?(qy-(float)(cy-1)*cw):1e30f);
    mg=fminf(mg,(cy<GC-1)?((float)(cy+2)*cw-qy):1e30f);
    mg=fminf(mg,(cz>0)?(qz-(float)(cz-1)*cw):1e30f);
    mg=fminf(mg,(cz<GC-1)?((float)(cz+2)*cw-qz):1e30f);
    float mg2=mg*mg*(1.0f-1e-5f);   // slack for dd rounding
    flg=!(D2<mg2);                  // at GC=8: ~never true
  }
  // safety-net fallback, expected ~0 queries
  unsigned long long mask=__ballot(flg);
  while(mask){
    int b=__ffsll((unsigned long long)mask)-1; mask&=mask-1;
    int qb=__shfl(q,b);
    float bx=__shfl(qx,b),by=__shfl(qy,b),bz=__shfl(qz,b),bs=__shfl(qs,b);
    float E0=1e30f,E1=1e30f,E2=1e30f; int F0=0x7fffffff,F1=0x7fffffff,F2=0x7fffffff;
    for(int j=lane;j<N;j+=64){
      float4 cv=c4[j];
      float dd=refdist(bx,by,bz,bs,cv);
      dd=(j==qb)?1e30f:dd;
      lexins(dd,j,E0,E1,E2,F0,F1,F2);
    }
    #pragma unroll
    for(int m=1;m<64;m<<=1){
      float e0=__shfl_xor(E0,m),e1=__shfl_xor(E1,m),e2=__shfl_xor(E2,m);
      int   f0=__shfl_xor(F0,m),f1=__shfl_xor(F1,m),f2=__shfl_xor(F2,m);
      lexins(e0,f0,E0,E1,E2,F0,F1,F2);
      lexins(e1,f1,E0,E1,E2,F0,F1,F2);
      lexins(e2,f2,E0,E1,E2,F0,F1,F2);
    }
    if(lane==b){ I0=F0; I1=F1; I2=F2; }
  }
  if(part==0){ knn[q*3+0]=I0; knn[q*3+1]=I1; knn[q*3+2]=I2; }

  // --- ew + dis for the wave's 2 queries (neighbor loads hoisted) ---
  for(int r=0;r<2;r++){
    int qi=__shfl(q,32*r);
    int s0=__shfl(I0,32*r), s1=__shfl(I1,32*r), s2=__shfl(I2,32*r);
    float xi=x[qi*64+lane];
    float xs0=x[s0*64+lane], xs1=x[s1*64+lane], xs2=x[s2*64+lane];
    float n0=xn[s0], n1=xn[s1], n2=xn[s2];
    float ni=xn[qi];
    float dt0=wsum(xs0*xi), dt1=wsum(xs1*xi), dt2=wsum(xs2*xi);
    float e0=1.f/(1.f+expf(-(dt0/(n0*ni))));
    float e1=1.f/(1.f+expf(-(dt1/(n1*ni))));
    float e2=1.f/(1.f+expf(-(dt2/(n2*ni))));
    if(lane==0){
      ew[qi*3+0]=e0; ew[qi*3+1]=e1; ew[qi*3+2]=e2;
      float ssum=((e0+e1)+e2);
      dis[qi]=1.f/sqrtf(ssum+1.0f);             // deg = 1 (self loop) + sum(ew)
    }
  }
}

// ---- K4: xa = weighted-agg(x); a1 = relu(LN(xa@W1 + b1)). Wave per 4 nodes. ----
// W column held in 64 VGPRs per lane (lane L owns W[:,L]) -> zero LDS reads
// for W. 2-deep software pipeline: node r+1's knn->gather chain (~2 L2
// latencies) overlaps node r's matvec + LN, since 4 waves/SIMD alone can't
// hide it.
__global__ __launch_bounds__(256) void agg1_w1(const float* __restrict__ x,
    const float* __restrict__ ew, const float* __restrict__ dis,
    const int* __restrict__ knn, const float* __restrict__ W1,
    const float* __restrict__ bb1, const float* __restrict__ gg,
    const float* __restrict__ gb, float* __restrict__ a1){
  __shared__ float rowbuf[4][64];
  int tid=threadIdx.x;
  int wave=tid>>6, lane=tid&63;
  float wcol[64];
  #pragma unroll
  for(int k=0;k<64;k++) wcol[k]=W1[k*64+lane];   // coalesced, L2-hit
  float bv=bb1[lane], gv=gg[lane], bv2=gb[lane];
  int nb=blockIdx.x*16+wave*4;
  float xrA,dAA,xsA0,xsA1,xsA2,wA0,wA1,wA2;
  float xrB,dBB,xsB0,xsB1,xsB2,wB0,wB1,wB2;
  { // prologue: stage node 0
    int i=nb;
    float di=dis[i]; dAA=di*di;
    xrA=x[i*64+lane];
    int s0=knn[i*3+0], s1=knn[i*3+1], s2=knn[i*3+2];
    xsA0=x[s0*64+lane]; xsA1=x[s1*64+lane]; xsA2=x[s2*64+lane];
    wA0=dis[s0]*ew[i*3+0]*di; wA1=dis[s1]*ew[i*3+1]*di; wA2=dis[s2]*ew[i*3+2]*di;
  }
  #pragma unroll
  for(int r=0;r<4;r++){
    if(r<3){ // stage node r+1 (loads issue before this iter's compute)
      int i=nb+r+1;
      float di=dis[i]; dBB=di*di;
      xrB=x[i*64+lane];
      int s0=knn[i*3+0], s1=knn[i*3+1], s2=knn[i*3+2];
      xsB0=x[s0*64+lane]; xsB1=x[s1*64+lane]; xsB2=x[s2*64+lane];
      wB0=dis[s0]*ew[i*3+0]*di; wB1=dis[s1]*ew[i*3+1]*di; wB2=dis[s2]*ew[i*3+2]*di;
    }
    float xa=xrA*dAA;
    xa=fmaf(xsA0,wA0,xa); xa=fmaf(xsA1,wA1,xa); xa=fmaf(xsA2,wA2,xa);
    rowbuf[wave][lane]=xa;                    // wave-synchronous LDS bounce
    const float4* rb=(const float4*)&rowbuf[wave][0];
    float acc=0.f;
    #pragma unroll
    for(int k4=0;k4<16;k4++){
      float4 av=rb[k4];                       // broadcast read
      acc=fmaf(av.x,wcol[k4*4+0],acc);
      acc=fmaf(av.y,wcol[k4*4+1],acc);
      acc=fmaf(av.z,wcol[k4*4+2],acc);
      acc=fmaf(av.w,wcol[k4*4+3],acc);
    }
    acc+=bv;
    float mu=wsum(acc)*(1.0f/64.0f);
    float dd=acc-mu;
    float var=wsum(dd*dd)*(1.0f/64.0f);
    float y=dd*(1.0f/sqrtf(var+1e-5f))*gv+bv2;
    a1[(nb+r)*64+lane]=fmaxf(y,0.0f);
    // rotate pipeline regs (all static -> stays in VGPRs)
    xrA=xrB; dAA=dBB;
    xsA0=xsB0; xsA1=xsB1; xsA2=xsB2;
    wA0=wB0; wA1=wB1; wA2=wB2;
  }
}

// ---- K5: aa = weighted-agg(a1); out = aa@W2 + b2 + 2x. Wave per 4 nodes. ----
// Same 2-deep pipeline as K4.
__global__ __launch_bounds__(256) void agg2_w2(const float* __restrict__ a1,
    const float* __restrict__ ew, const float* __restrict__ dis,
    const int* __restrict__ knn, const float* __restrict__ W2,
    const float* __restrict__ bb2, const float* __restrict__ x,
    float* __restrict__ out){
  __shared__ float rowbuf[4][64];
  int tid=threadIdx.x;
  int wave=tid>>6, lane=tid&63;
  float wcol[64];
  #pragma unroll
  for(int k=0;k<64;k++) wcol[k]=W2[k*64+lane];   // coalesced, L2-hit
  float bv=bb2[lane];
  int nb=blockIdx.x*16+wave*4;
  float xrA,dAA,xsA0,xsA1,xsA2,wA0,wA1,wA2;
  float xrB,dBB,xsB0,xsB1,xsB2,wB0,wB1,wB2;
  {
    int i=nb;
    float di=dis[i]; dAA=di*di;
    xrA=a1[i*64+lane];
    int s0=knn[i*3+0], s1=knn[i*3+1], s2=knn[i*3+2];
    xsA0=a1[s0*64+lane]; xsA1=a1[s1*64+lane]; xsA2=a1[s2*64+lane];
    wA0=dis[s0]*ew[i*3+0]*di; wA1=dis[s1]*ew[i*3+1]*di; wA2=dis[s2]*ew[i*3+2]*di;
  }
  #pragma unroll
  for(int r=0;r<4;r++){
    if(r<3){
      int i=nb+r+1;
      float di=dis[i]; dBB=di*di;
      xrB=a1[i*64+lane];
      int s0=knn[i*3+0], s1=knn[i*3+1], s2=knn[i*3+2];
      xsB0=a1[s0*64+lane]; xsB1=a1[s1*64+lane]; xsB2=a1[s2*64+lane];
      wB0=dis[s0]*ew[i*3+0]*di; wB1=dis[s1]*ew[i*3+1]*di; wB2=dis[s2]*ew[i*3+2]*di;
    }
    float aa=xrA*dAA;
    aa=fmaf(xsA0,wA0,aa); aa=fmaf(xsA1,wA1,aa); aa=fmaf(xsA2,wA2,aa);
    rowbuf[wave][lane]=aa;
    const float4* rb=(const float4*)&rowbuf[wave][0];
    float acc=0.f;
    #pragma unroll
    for(int k4=0;k4<16;k4++){
      float4 av=rb[k4];
      acc=fmaf(av.x,wcol[k4*4+0],acc);
      acc=fmaf(av.y,wcol[k4*4+1],acc);
      acc=fmaf(av.z,wcol[k4*4+2],acc);
      acc=fmaf(av.w,wcol[k4*4+3],acc);
    }
    acc+=bv;
    float xv=x[(nb+r)*64+lane];
    out[(nb+r)*64+lane]=(acc+xv)+xv;  // (gcn2 + x) + shortcut, shortcut == x
    xrA=xrB; dAA=dBB;
    xsA0=xsB0; xsA1=xsB1; xsA2=xsB2;
    wA0=wB0; wA1=wB1; wA2=wB2;
  }
}

extern "C" void kernel_launch(void* const* d_in, const int* in_sizes, int n_in,
                              void* d_out, int out_size, void* d_ws, size_t ws_size,
                              hipStream_t stream){
  const float* feat  =(const float*)d_in[0];
  // d_in[1] edge_index_tran, d_in[2] edge_attr_rpe, d_in[3] norm_index: unused by reference
  const float* coords=(const float*)d_in[4];
  const float* g1 =(const float*)d_in[5];
  const float* b1n=(const float*)d_in[6];
  const float* g2 =(const float*)d_in[7];
  const float* b2n=(const float*)d_in[8];
  const float* gg =(const float*)d_in[9];
  const float* gb =(const float*)d_in[10];
  const float* W1 =(const float*)d_in[11];
  const float* bb1=(const float*)d_in[12];
  const float* W2 =(const float*)d_in[13];
  const float* bb2=(const float*)d_in[14];
  float* out=(float*)d_out;

  char* ws=(char*)d_ws;
  size_t o=0;
  float*  x      =(float*) (ws+o); o+=(size_t)N*64*4;    // post-LN2 features
  float*  a1     =(float*) (ws+o); o+=(size_t)N*64*4;    // activated GCN1 output
  float*  xn     =(float*) (ws+o); o+=(size_t)N*4;       // row norms of x
  float*  ew     =(float*) (ws+o); o+=(size_t)N*3*4;     // knn edge weights
  float*  dis    =(float*) (ws+o); o+=(size_t)N*4;       // 1/sqrt(deg)
  int*    knn    =(int*)   (ws+o); o+=(size_t)N*3*4;     // neighbor indices
  float4* c4     =(float4*)(ws+o); o+=(size_t)N*16;      // (x,y,z,sq) original order
  float4* sc4    =(float4*)(ws+o); o+=(size_t)N*16;      // cell-sorted
  int*    sidx   =(int*)   (ws+o); o+=(size_t)N*4;       // sorted -> original
  int*    cellSt =(int*)   (ws+o); o+=(size_t)(NCELL+1)*4;
  o=(o+255)&~(size_t)255;
  int*    cnt    =(int*)   (ws+o); o+=(size_t)NCELL*4;   // histogram (memset 0)
  int*    cursor =(int*)   (ws+o); o+=(size_t)NCELL*4;   // scatter cursors (memset 0)
  (void)ws_size; (void)in_sizes; (void)n_in; (void)out_size;

  // zero cnt+cursor (contiguous, 4KB) -- graph-capturable memset node
  hipMemsetAsync((void*)cnt, 0, (size_t)2*NCELL*4, stream);
  hipLaunchKernelGGL(ln_kernel, dim3(N/4),   dim3(256), 0, stream, feat,g1,b1n,g2,b2n,coords,x,xn,c4,cnt);
  hipLaunchKernelGGL(scatter_k, dim3(N/256), dim3(256), 0, stream, c4,cnt,cursor,sc4,sidx,cellSt);
  hipLaunchKernelGGL(knn_ew,    dim3(2048),  dim3(256), 0, stream, sc4,sidx,cellSt,c4,x,xn,knn,ew,dis);
  hipLaunchKernelGGL(agg1_w1,   dim3(N/16),  dim3(256), 0, stream, x,ew,dis,knn,W1,bb1,gg,gb,a1);
  hipLaunchKernelGGL(agg2_w2,   dim3(N/16),  dim3(256), 0, stream, a1,ew,dis,knn,W2,bb2,x,out);
}